// Round 9
// baseline (374.557 us; speedup 1.0000x reference)
//
#include <hip/hip_runtime.h>

#define NN 50000
#define NE 800000
#define NG 64
#define NCHUNK 64
#define CHUNK 12500     // NE / NCHUNK
#define HALF 25000      // NN / 2

typedef short short8 __attribute__((ext_vector_type(8)));
typedef float f32x4 __attribute__((ext_vector_type(4)));

// bf16 helpers (RTNE)
__device__ __forceinline__ unsigned short f2bf(float f) {
    unsigned int u = __float_as_uint(f);
    u = (u + 0x7FFFu + ((u >> 16) & 1u)) >> 16;
    return (unsigned short)u;
}
__device__ __forceinline__ float bf2f(unsigned short h) {
    return __uint_as_float((unsigned int)h << 16);
}

// ---------------- chunk histogram via LDS (packed 2x16-bit counters) ----------------
__global__ __launch_bounds__(1024) void k_hist(const int* __restrict__ ei,
                                               unsigned short* __restrict__ rank,
                                               unsigned short* __restrict__ percnt) {
    __shared__ unsigned int cnt[HALF / 2];          // 50 KB: 2 ushort counters per word
    const int b = blockIdx.x;
    const int dbase = blockIdx.y * HALF;
    const int tid = threadIdx.x;
    for (int i = tid; i < HALF / 2; i += 1024) cnt[i] = 0;
    __syncthreads();
    const int e0 = b * CHUNK;
    for (int i = tid; i < CHUNK; i += 1024) {
        const int d = ei[NE + e0 + i];
        const int local = d - dbase;
        if ((unsigned)local < (unsigned)HALF) {
            const unsigned int old = atomicAdd(&cnt[local >> 1], 1u << ((local & 1) * 16));
            rank[e0 + i] = (unsigned short)((old >> ((local & 1) * 16)) & 0xFFFFu);
        }
    }
    __syncthreads();
    unsigned int* dst = (unsigned int*)&percnt[(size_t)b * NN + dbase];
    for (int i = tid; i < HALF / 2; i += 1024) dst[i] = cnt[i];
}

// ---------------- per-dst exclusive scan over chunks (in-place) + degcnt + dinv ----------------
__global__ __launch_bounds__(256) void k_colscan(unsigned short* __restrict__ percnt,
                                                 int* __restrict__ degcnt, float* __restrict__ dinv) {
    const int d = blockIdx.x * 256 + threadIdx.x;
    if (d >= NN) return;
    int acc = 0;
#pragma unroll 8
    for (int b = 0; b < NCHUNK; ++b) {
        const int c = percnt[(size_t)b * NN + d];
        percnt[(size_t)b * NN + d] = (unsigned short)acc;
        acc += c;
    }
    degcnt[d] = acc;
    dinv[d] = (float)(1.0 / sqrt((double)acc + 1.0));
}

// ---------------- prefix scan (3 stages) ----------------
__global__ __launch_bounds__(1024) void k_scan1(const int* __restrict__ cnt, int* __restrict__ row_ptr,
                                                int* __restrict__ blk_sums) {
    __shared__ int s[1024];
    const int tid = threadIdx.x;
    const int i = blockIdx.x * 1024 + tid;
    int v = (i < NN) ? cnt[i] : 0;
    s[tid] = v;
    __syncthreads();
    for (int off = 1; off < 1024; off <<= 1) {
        int t = (tid >= off) ? s[tid - off] : 0;
        __syncthreads();
        s[tid] += t;
        __syncthreads();
    }
    if (i < NN) row_ptr[i] = s[tid] - v;
    if (tid == 1023) blk_sums[blockIdx.x] = s[1023];
}

__global__ __launch_bounds__(64) void k_scan2(int* __restrict__ blk_sums, int nb) {
    int l = threadIdx.x;
    int v = (l < nb) ? blk_sums[l] : 0;
    int incl = v;
    for (int off = 1; off < 64; off <<= 1) {
        int t = __shfl_up(incl, off, 64);
        if (l >= off) incl += t;
    }
    if (l < nb) blk_sums[l] = incl - v;
}

__global__ __launch_bounds__(1024) void k_scan3(int* __restrict__ row_ptr, const int* __restrict__ blk_sums) {
    int i = blockIdx.x * 1024 + threadIdx.x;
    if (i < NN) row_ptr[i] += blk_sums[blockIdx.x];
    if (i == 0) row_ptr[NN] = NE;
}

// ---------------- CSR fill: atomic-free ----------------
__global__ __launch_bounds__(256) void k_fill3(const int* __restrict__ ei, const int* __restrict__ row_ptr,
                                               const unsigned short* __restrict__ rank,
                                               const unsigned short* __restrict__ offs,
                                               int* __restrict__ csr_src) {
    const int e = blockIdx.x * 256 + threadIdx.x;
    if (e >= NE) return;
    const int s = ei[e];
    const int d = ei[NE + e];
    const int b = e / CHUNK;
    const int pos = row_ptr[d] + (int)offs[(size_t)b * NN + d] + (int)rank[e];
    csr_src[pos] = s;
}

// ---------------- bf16 MFMA GEMM: C[M x DO](bf16) = A[M x 128](f32) @ W[128 x DO](f32) ----------------
template <int DO>
__global__ __launch_bounds__(256) void k_gemm_mfma(const float* __restrict__ A, const float* __restrict__ W,
                                                   unsigned short* __restrict__ C, int M) {
    constexpr int NT = DO / 16;
    constexpr int LDK = 136;
    __shared__ __align__(16) unsigned short As[64 * LDK];
    __shared__ __align__(16) unsigned short Wt[DO * LDK];
    const int tid = threadIdx.x;
    const int row0 = blockIdx.x * 64;

    for (int task = tid; task < 64 * (DO / 4); task += 256) {
        const int k0 = (task / (DO / 4)) * 2;
        const int n4 = (task % (DO / 4)) * 4;
        const float4 wa = *(const float4*)&W[(size_t)k0 * DO + n4];
        const float4 wb = *(const float4*)&W[(size_t)(k0 + 1) * DO + n4];
        const float pa[4] = {wa.x, wa.y, wa.z, wa.w};
        const float pb[4] = {wb.x, wb.y, wb.z, wb.w};
#pragma unroll
        for (int i = 0; i < 4; ++i) {
            const unsigned int pk = (unsigned int)f2bf(pa[i]) | ((unsigned int)f2bf(pb[i]) << 16);
            *(unsigned int*)&Wt[(n4 + i) * LDK + k0] = pk;
        }
    }
    {
        const int r = tid >> 2;
        const int ks = (tid & 3) * 32;
        const int grow = row0 + r;
#pragma unroll
        for (int q = 0; q < 8; ++q) {
            float4 v = make_float4(0.f, 0.f, 0.f, 0.f);
            if (grow < M) v = *(const float4*)&A[(size_t)grow * 128 + ks + q * 4];
            const unsigned long long pk =
                (unsigned long long)f2bf(v.x) | ((unsigned long long)f2bf(v.y) << 16) |
                ((unsigned long long)f2bf(v.z) << 32) | ((unsigned long long)f2bf(v.w) << 48);
            *(unsigned long long*)&As[r * LDK + ks + q * 4] = pk;
        }
    }
    __syncthreads();

    const int l = tid & 63;
    const int w = tid >> 6;
    const int lr = l & 15;
    const int lg = l >> 4;
    f32x4 acc[NT];
#pragma unroll
    for (int nt = 0; nt < NT; ++nt) acc[nt] = (f32x4){0.f, 0.f, 0.f, 0.f};

#pragma unroll
    for (int kk = 0; kk < 128; kk += 32) {
        const short8 af = *(const short8*)&As[(w * 16 + lr) * LDK + kk + lg * 8];
#pragma unroll
        for (int nt = 0; nt < NT; ++nt) {
            const short8 bfv = *(const short8*)&Wt[(nt * 16 + lr) * LDK + kk + lg * 8];
            acc[nt] = __builtin_amdgcn_mfma_f32_16x16x32_bf16(af, bfv, acc[nt], 0, 0, 0);
        }
    }

#pragma unroll
    for (int nt = 0; nt < NT; ++nt) {
#pragma unroll
        for (int r = 0; r < 4; ++r) {
            const int grow = row0 + w * 16 + lg * 4 + r;
            if (grow < M) C[(size_t)grow * DO + nt * 16 + lr] = f2bf(acc[nt][r]);
        }
    }
}

// ---------------- aggregation: persistent grid, SEQUENTIAL feature-chunk phases ----------------
// All ~782 blocks are co-resident (3/CU) and sweep chunk 0..NCH-1 in rough lockstep, so the
// machine-wide concurrent gather window is 50000 x 64B = 3.2MB < 4MB per-XCD L2.
// 8 lanes/node x 4 feats (ushort4 = 8B); 32 nodes/block-batch, 2 batches/block/phase.
// f32 accumulation (CSR order jitter ~1e-7 << 4.4e-4 margin).
template <int D, bool RELU>
__global__ __launch_bounds__(256) void k_agg(const unsigned short* __restrict__ T, const float* __restrict__ bias,
                                             const float* __restrict__ dinv, const int* __restrict__ row_ptr,
                                             const int* __restrict__ csr_src,
                                             float* __restrict__ out) {
    constexpr int NCH = D / 32;         // feature chunks: 4 (D=128), 2 (D=64)
    const int tid = threadIdx.x;
    const int lane = tid & 7;           // 8 lanes/node
    const int grp = tid >> 3;           // 32 nodes/batch
    const int nbase = blockIdx.x * 64;

#pragma unroll
    for (int ch = 0; ch < NCH; ++ch) {
        const int f0 = ch * 32 + lane * 4;
#pragma unroll
        for (int half = 0; half < 2; ++half) {
            const int n = nbase + half * 32 + grp;
            if (n >= NN) continue;
            const float di_n = dinv[n];
            float a0 = 0.f, a1 = 0.f, a2 = 0.f, a3 = 0.f;
            const int beg = row_ptr[n];
            const int end = row_ptr[n + 1];
            int e = beg;
            for (; e + 4 <= end; e += 4) {
                const int s0 = csr_src[e + 0], s1 = csr_src[e + 1], s2 = csr_src[e + 2], s3 = csr_src[e + 3];
                const float w0 = dinv[s0] * di_n, w1 = dinv[s1] * di_n, w2 = dinv[s2] * di_n, w3 = dinv[s3] * di_n;
                const ushort4 v0 = *(const ushort4*)&T[(size_t)s0 * D + f0];
                const ushort4 v1 = *(const ushort4*)&T[(size_t)s1 * D + f0];
                const ushort4 v2 = *(const ushort4*)&T[(size_t)s2 * D + f0];
                const ushort4 v3 = *(const ushort4*)&T[(size_t)s3 * D + f0];
                a0 = fmaf(w0, bf2f(v0.x), a0); a1 = fmaf(w0, bf2f(v0.y), a1);
                a2 = fmaf(w0, bf2f(v0.z), a2); a3 = fmaf(w0, bf2f(v0.w), a3);
                a0 = fmaf(w1, bf2f(v1.x), a0); a1 = fmaf(w1, bf2f(v1.y), a1);
                a2 = fmaf(w1, bf2f(v1.z), a2); a3 = fmaf(w1, bf2f(v1.w), a3);
                a0 = fmaf(w2, bf2f(v2.x), a0); a1 = fmaf(w2, bf2f(v2.y), a1);
                a2 = fmaf(w2, bf2f(v2.z), a2); a3 = fmaf(w2, bf2f(v2.w), a3);
                a0 = fmaf(w3, bf2f(v3.x), a0); a1 = fmaf(w3, bf2f(v3.y), a1);
                a2 = fmaf(w3, bf2f(v3.z), a2); a3 = fmaf(w3, bf2f(v3.w), a3);
            }
            for (; e < end; ++e) {
                const int s = csr_src[e];
                const float w = dinv[s] * di_n;
                const ushort4 v = *(const ushort4*)&T[(size_t)s * D + f0];
                a0 = fmaf(w, bf2f(v.x), a0); a1 = fmaf(w, bf2f(v.y), a1);
                a2 = fmaf(w, bf2f(v.z), a2); a3 = fmaf(w, bf2f(v.w), a3);
            }
            // self-loop
            {
                const float w = di_n * di_n;
                const ushort4 v = *(const ushort4*)&T[(size_t)n * D + f0];
                a0 = fmaf(w, bf2f(v.x), a0); a1 = fmaf(w, bf2f(v.y), a1);
                a2 = fmaf(w, bf2f(v.z), a2); a3 = fmaf(w, bf2f(v.w), a3);
            }
            const float4 b = *(const float4*)&bias[f0];
            float4 r;
            r.x = a0 + b.x; r.y = a1 + b.y; r.z = a2 + b.z; r.w = a3 + b.w;
            if (RELU) {
                r.x = fmaxf(r.x, 0.f);
                r.y = fmaxf(r.y, 0.f);
                r.z = fmaxf(r.z, 0.f);
                r.w = fmaxf(r.w, 0.f);
            }
            *(float4*)&out[(size_t)n * D + f0] = r;
        }
    }
}

// ---------------- mean pool (batch sorted), f64 accum ----------------
__global__ __launch_bounds__(256) void k_pool(const float* __restrict__ h, const int* __restrict__ batch,
                                              double* __restrict__ sums, int* __restrict__ cnts) {
    const int NB = 256;
    const int n0 = blockIdx.x * NB;
    const int d = threadIdx.x & 63;
    const int sub = threadIdx.x >> 6;
    double acc = 0.0;
    int cnt = 0;
    int cur = -1;
    for (int i = sub; i < NB; i += 4) {
        int n = n0 + i;
        if (n >= NN) break;
        int g = batch[n];
        if (g != cur) {
            if (cur >= 0) {
                atomicAdd(&sums[cur * 64 + d], acc);
                if (d == 0) atomicAdd(&cnts[cur], cnt);
            }
            cur = g;
            acc = 0.0;
            cnt = 0;
        }
        acc += (double)h[(size_t)n * 64 + d];
        cnt++;
    }
    if (cur >= 0) {
        atomicAdd(&sums[cur * 64 + d], acc);
        if (d == 0) atomicAdd(&cnts[cur], cnt);
    }
}

__global__ __launch_bounds__(256) void k_final(const double* __restrict__ sums, const int* __restrict__ cnts,
                                               float* __restrict__ out) {
    int i = blockIdx.x * 256 + threadIdx.x;
    if (i >= NG * 64) return;
    int g = i >> 6;
    double c = (double)max(cnts[g], 1);
    out[i] = (float)(sums[i] / c);
}

extern "C" void kernel_launch(void* const* d_in, const int* in_sizes, int n_in,
                              void* d_out, int out_size, void* d_ws, size_t ws_size,
                              hipStream_t stream) {
    (void)in_sizes; (void)n_in; (void)out_size; (void)ws_size;
    const float* x     = (const float*)d_in[0];
    const int*   ei    = (const int*)d_in[1];
    const int*   batch = (const int*)d_in[2];
    const float* W1    = (const float*)d_in[3];
    const float* b1    = (const float*)d_in[4];
    const float* W2    = (const float*)d_in[5];
    const float* b2    = (const float*)d_in[6];
    const float* W3    = (const float*)d_in[7];
    const float* b3    = (const float*)d_in[8];
    float* out = (float*)d_out;

    // workspace layout
    char* w = (char*)d_ws;
    char*  zbase = w;
    double* psums  = (double*)w;        w += (size_t)NG * 64 * 8;
    int*    pcnts  = (int*)w;           w += 256;
    size_t zbytes = (size_t)(w - zbase);
    int*    degcnt = (int*)w;           w += (size_t)NN * 4;
    float*  dinv   = (float*)w;         w += (size_t)NN * 4;
    int*    row_ptr = (int*)w;          w += (size_t)(NN + 4) * 4;
    int*    blk_sums = (int*)w;         w += 64 * 4;
    unsigned short* rank   = (unsigned short*)w;  w += (size_t)NE * 2;
    unsigned short* percnt = (unsigned short*)w;  w += (size_t)NCHUNK * NN * 2;
    int*    csr_src = (int*)w;          w += (size_t)NE * 4;
    unsigned short* bufT = (unsigned short*)w;  w += (size_t)NN * 128 * 2;
    float* bufA = (float*)w;            w += (size_t)NN * 128 * 4;

    hipMemsetAsync(zbase, 0, zbytes, stream);

    // atomic-free CSR build
    k_hist<<<dim3(NCHUNK, 2), 1024, 0, stream>>>(ei, rank, percnt);
    k_colscan<<<(NN + 255) / 256, 256, 0, stream>>>(percnt, degcnt, dinv);
    const int nb_scan = (NN + 1023) / 1024;   // 49
    k_scan1<<<nb_scan, 1024, 0, stream>>>(degcnt, row_ptr, blk_sums);
    k_scan2<<<1, 64, 0, stream>>>(blk_sums, nb_scan);
    k_scan3<<<nb_scan, 1024, 0, stream>>>(row_ptr, blk_sums);
    k_fill3<<<(NE + 255) / 256, 256, 0, stream>>>(ei, row_ptr, rank, percnt, csr_src);

    const int gemm_grid = (NN + 63) / 64;     // 782
    const int agg_grid  = (NN + 63) / 64;     // 782 persistent-ish blocks (~3/CU)
    // layer 1
    k_gemm_mfma<128><<<gemm_grid, 256, 0, stream>>>(x, W1, bufT, NN);
    k_agg<128, true><<<agg_grid, 256, 0, stream>>>(bufT, b1, dinv, row_ptr, csr_src, bufA);
    // layer 2
    k_gemm_mfma<128><<<gemm_grid, 256, 0, stream>>>(bufA, W2, bufT, NN);
    k_agg<128, true><<<agg_grid, 256, 0, stream>>>(bufT, b2, dinv, row_ptr, csr_src, bufA);
    // layer 3 (no relu, D_OUT=64)
    k_gemm_mfma<64><<<gemm_grid, 256, 0, stream>>>(bufA, W3, bufT, NN);
    k_agg<64, false><<<agg_grid, 256, 0, stream>>>(bufT, b3, dinv, row_ptr, csr_src, bufA);
    // pool
    k_pool<<<(NN + 255) / 256, 256, 0, stream>>>(bufA, batch, psums, pcnts);
    k_final<<<(NG * 64 + 255) / 256, 256, 0, stream>>>(psums, pcnts, out);
}

// Round 10
// 238.172 us; speedup vs baseline: 1.5726x; 1.5726x over previous
//
#include <hip/hip_runtime.h>

#define NN 50000
#define NE 800000
#define NG 64
#define NCHUNK 64
#define CHUNK 12500     // NE / NCHUNK
#define HALF 25000      // NN / 2

typedef short short8 __attribute__((ext_vector_type(8)));
typedef float f32x4 __attribute__((ext_vector_type(4)));

// bf16 helpers (RTNE)
__device__ __forceinline__ unsigned short f2bf(float f) {
    unsigned int u = __float_as_uint(f);
    u = (u + 0x7FFFu + ((u >> 16) & 1u)) >> 16;
    return (unsigned short)u;
}
__device__ __forceinline__ float bf2f(unsigned short h) {
    return __uint_as_float((unsigned int)h << 16);
}
// accumulate 8 bf16 feats (one uint4) with weight w
__device__ __forceinline__ void fma8(float* acc, float w, const uint4 v) {
    const unsigned int u0 = v.x, u1 = v.y, u2 = v.z, u3 = v.w;
    acc[0] = fmaf(w, __uint_as_float(u0 << 16), acc[0]);
    acc[1] = fmaf(w, __uint_as_float(u0 & 0xFFFF0000u), acc[1]);
    acc[2] = fmaf(w, __uint_as_float(u1 << 16), acc[2]);
    acc[3] = fmaf(w, __uint_as_float(u1 & 0xFFFF0000u), acc[3]);
    acc[4] = fmaf(w, __uint_as_float(u2 << 16), acc[4]);
    acc[5] = fmaf(w, __uint_as_float(u2 & 0xFFFF0000u), acc[5]);
    acc[6] = fmaf(w, __uint_as_float(u3 << 16), acc[6]);
    acc[7] = fmaf(w, __uint_as_float(u3 & 0xFFFF0000u), acc[7]);
}

// ---------------- chunk histogram via LDS (packed 2x16-bit counters) ----------------
__global__ __launch_bounds__(1024) void k_hist(const int* __restrict__ ei,
                                               unsigned short* __restrict__ rank,
                                               unsigned short* __restrict__ percnt) {
    __shared__ unsigned int cnt[HALF / 2];          // 50 KB
    const int b = blockIdx.x;
    const int dbase = blockIdx.y * HALF;
    const int tid = threadIdx.x;
    for (int i = tid; i < HALF / 2; i += 1024) cnt[i] = 0;
    __syncthreads();
    const int e0 = b * CHUNK;
    for (int i = tid; i < CHUNK; i += 1024) {
        const int d = ei[NE + e0 + i];
        const int local = d - dbase;
        if ((unsigned)local < (unsigned)HALF) {
            const unsigned int old = atomicAdd(&cnt[local >> 1], 1u << ((local & 1) * 16));
            rank[e0 + i] = (unsigned short)((old >> ((local & 1) * 16)) & 0xFFFFu);
        }
    }
    __syncthreads();
    unsigned int* dst = (unsigned int*)&percnt[(size_t)b * NN + dbase];
    for (int i = tid; i < HALF / 2; i += 1024) dst[i] = cnt[i];
}

// ---------------- per-dst exclusive scan over chunks (in-place) + degcnt + dinv ----------------
__global__ __launch_bounds__(256) void k_colscan(unsigned short* __restrict__ percnt,
                                                 int* __restrict__ degcnt, float* __restrict__ dinv) {
    const int d = blockIdx.x * 256 + threadIdx.x;
    if (d >= NN) return;
    int acc = 0;
#pragma unroll 8
    for (int b = 0; b < NCHUNK; ++b) {
        const int c = percnt[(size_t)b * NN + d];
        percnt[(size_t)b * NN + d] = (unsigned short)acc;
        acc += c;
    }
    degcnt[d] = acc;
    dinv[d] = (float)(1.0 / sqrt((double)acc + 1.0));
}

// ---------------- prefix scan (3 stages) ----------------
__global__ __launch_bounds__(1024) void k_scan1(const int* __restrict__ cnt, int* __restrict__ row_ptr,
                                                int* __restrict__ blk_sums) {
    __shared__ int s[1024];
    const int tid = threadIdx.x;
    const int i = blockIdx.x * 1024 + tid;
    int v = (i < NN) ? cnt[i] : 0;
    s[tid] = v;
    __syncthreads();
    for (int off = 1; off < 1024; off <<= 1) {
        int t = (tid >= off) ? s[tid - off] : 0;
        __syncthreads();
        s[tid] += t;
        __syncthreads();
    }
    if (i < NN) row_ptr[i] = s[tid] - v;
    if (tid == 1023) blk_sums[blockIdx.x] = s[1023];
}

__global__ __launch_bounds__(64) void k_scan2(int* __restrict__ blk_sums, int nb) {
    int l = threadIdx.x;
    int v = (l < nb) ? blk_sums[l] : 0;
    int incl = v;
    for (int off = 1; off < 64; off <<= 1) {
        int t = __shfl_up(incl, off, 64);
        if (l >= off) incl += t;
    }
    if (l < nb) blk_sums[l] = incl - v;
}

__global__ __launch_bounds__(1024) void k_scan3(int* __restrict__ row_ptr, const int* __restrict__ blk_sums) {
    int i = blockIdx.x * 1024 + threadIdx.x;
    if (i < NN) row_ptr[i] += blk_sums[blockIdx.x];
    if (i == 0) row_ptr[NN] = NE;
}

// ---------------- CSR fill: atomic-free ----------------
__global__ __launch_bounds__(256) void k_fill3(const int* __restrict__ ei, const int* __restrict__ row_ptr,
                                               const unsigned short* __restrict__ rank,
                                               const unsigned short* __restrict__ offs,
                                               int* __restrict__ csr_src) {
    const int e = blockIdx.x * 256 + threadIdx.x;
    if (e >= NE) return;
    const int s = ei[e];
    const int d = ei[NE + e];
    const int b = e / CHUNK;
    const int pos = row_ptr[d] + (int)offs[(size_t)b * NN + d] + (int)rank[e];
    csr_src[pos] = s;
}

// ---------------- bf16 MFMA GEMM: C[M x DO](bf16) = A[M x 128] @ W[128 x DO](f32) ----------------
// AF32: A is f32 (layer 1, converts in staging); else A is bf16 (straight copy).
template <int DO, bool AF32>
__global__ __launch_bounds__(256) void k_gemm_mfma(const void* __restrict__ Ain, const float* __restrict__ W,
                                                   unsigned short* __restrict__ C, int M) {
    constexpr int NT = DO / 16;
    constexpr int LDK = 136;
    __shared__ __align__(16) unsigned short As[64 * LDK];
    __shared__ __align__(16) unsigned short Wt[DO * LDK];
    const int tid = threadIdx.x;
    const int row0 = blockIdx.x * 64;

    // stage W transposed -> Wt[n][k] bf16
    for (int task = tid; task < 64 * (DO / 4); task += 256) {
        const int k0 = (task / (DO / 4)) * 2;
        const int n4 = (task % (DO / 4)) * 4;
        const float4 wa = *(const float4*)&W[(size_t)k0 * DO + n4];
        const float4 wb = *(const float4*)&W[(size_t)(k0 + 1) * DO + n4];
        const float pa[4] = {wa.x, wa.y, wa.z, wa.w};
        const float pb[4] = {wb.x, wb.y, wb.z, wb.w};
#pragma unroll
        for (int i = 0; i < 4; ++i) {
            const unsigned int pk = (unsigned int)f2bf(pa[i]) | ((unsigned int)f2bf(pb[i]) << 16);
            *(unsigned int*)&Wt[(n4 + i) * LDK + k0] = pk;
        }
    }
    // stage A tile -> As[row][k] bf16 (4 threads/row)
    if constexpr (AF32) {
        const float* A = (const float*)Ain;
        const int r = tid >> 2;
        const int ks = (tid & 3) * 32;
        const int grow = row0 + r;
#pragma unroll
        for (int q = 0; q < 8; ++q) {
            float4 v = make_float4(0.f, 0.f, 0.f, 0.f);
            if (grow < M) v = *(const float4*)&A[(size_t)grow * 128 + ks + q * 4];
            const unsigned long long pk =
                (unsigned long long)f2bf(v.x) | ((unsigned long long)f2bf(v.y) << 16) |
                ((unsigned long long)f2bf(v.z) << 32) | ((unsigned long long)f2bf(v.w) << 48);
            *(unsigned long long*)&As[r * LDK + ks + q * 4] = pk;
        }
    } else {
        const unsigned short* A = (const unsigned short*)Ain;
        const int r = tid >> 2;
        const int c0 = (tid & 3) * 32;
        const int grow = row0 + r;
#pragma unroll
        for (int q = 0; q < 4; ++q) {
            uint4 v = make_uint4(0, 0, 0, 0);
            if (grow < M) v = *(const uint4*)&A[(size_t)grow * 128 + c0 + q * 8];
            *(uint4*)&As[r * LDK + c0 + q * 8] = v;
        }
    }
    __syncthreads();

    const int l = tid & 63;
    const int w = tid >> 6;
    const int lr = l & 15;
    const int lg = l >> 4;
    f32x4 acc[NT];
#pragma unroll
    for (int nt = 0; nt < NT; ++nt) acc[nt] = (f32x4){0.f, 0.f, 0.f, 0.f};

#pragma unroll
    for (int kk = 0; kk < 128; kk += 32) {
        const short8 af = *(const short8*)&As[(w * 16 + lr) * LDK + kk + lg * 8];
#pragma unroll
        for (int nt = 0; nt < NT; ++nt) {
            const short8 bfv = *(const short8*)&Wt[(nt * 16 + lr) * LDK + kk + lg * 8];
            acc[nt] = __builtin_amdgcn_mfma_f32_16x16x32_bf16(af, bfv, acc[nt], 0, 0, 0);
        }
    }

#pragma unroll
    for (int nt = 0; nt < NT; ++nt) {
#pragma unroll
        for (int r = 0; r < 4; ++r) {
            const int grow = row0 + w * 16 + lg * 4 + r;
            if (grow < M) C[(size_t)grow * DO + nt * 16 + lr] = f2bf(acc[nt][r]);
        }
    }
}

// ---------------- aggregation (round-7 structure, 16B gathers, f32 accum, bf16 out) ----------------
// G = D/8 lanes per node, each lane owns 8 feats (16B). out = sum_e dinv[s]*dinv[n]*T[s] + dinv^2*T[n] + b (+relu)
template <int D, bool RELU>
__global__ __launch_bounds__(256) void k_agg(const unsigned short* __restrict__ T, const float* __restrict__ bias,
                                             const float* __restrict__ dinv, const int* __restrict__ row_ptr,
                                             const int* __restrict__ csr_src,
                                             unsigned short* __restrict__ out) {
    constexpr int G = D / 8;        // 16 (D=128) / 8 (D=64)
    constexpr int NPB = 256 / G;    // 16 / 32 nodes per block
    const int tid = threadIdx.x;
    const int lane = tid % G;
    const int grp = tid / G;
    const int n = blockIdx.x * NPB + grp;
    if (n >= NN) return;
    const int f0 = lane * 8;

    const float di_n = dinv[n];
    float acc[8] = {0.f, 0.f, 0.f, 0.f, 0.f, 0.f, 0.f, 0.f};
    const int beg = row_ptr[n];
    const int end = row_ptr[n + 1];
    int e = beg;
    for (; e + 4 <= end; e += 4) {
        const int s0 = csr_src[e + 0], s1 = csr_src[e + 1], s2 = csr_src[e + 2], s3 = csr_src[e + 3];
        const float w0 = dinv[s0] * di_n, w1 = dinv[s1] * di_n, w2 = dinv[s2] * di_n, w3 = dinv[s3] * di_n;
        const uint4 v0 = *(const uint4*)&T[(size_t)s0 * D + f0];
        const uint4 v1 = *(const uint4*)&T[(size_t)s1 * D + f0];
        const uint4 v2 = *(const uint4*)&T[(size_t)s2 * D + f0];
        const uint4 v3 = *(const uint4*)&T[(size_t)s3 * D + f0];
        fma8(acc, w0, v0);
        fma8(acc, w1, v1);
        fma8(acc, w2, v2);
        fma8(acc, w3, v3);
    }
    for (; e < end; ++e) {
        const int s = csr_src[e];
        const float w = dinv[s] * di_n;
        const uint4 v = *(const uint4*)&T[(size_t)s * D + f0];
        fma8(acc, w, v);
    }
    // self-loop
    {
        const uint4 v = *(const uint4*)&T[(size_t)n * D + f0];
        fma8(acc, di_n * di_n, v);
    }
    // bias
    const float4 b0 = *(const float4*)&bias[f0];
    const float4 b1 = *(const float4*)&bias[f0 + 4];
    acc[0] += b0.x; acc[1] += b0.y; acc[2] += b0.z; acc[3] += b0.w;
    acc[4] += b1.x; acc[5] += b1.y; acc[6] += b1.z; acc[7] += b1.w;
    if (RELU) {
#pragma unroll
        for (int j = 0; j < 8; ++j) acc[j] = fmaxf(acc[j], 0.f);
    }
    uint4 o;
    o.x = (unsigned int)f2bf(acc[0]) | ((unsigned int)f2bf(acc[1]) << 16);
    o.y = (unsigned int)f2bf(acc[2]) | ((unsigned int)f2bf(acc[3]) << 16);
    o.z = (unsigned int)f2bf(acc[4]) | ((unsigned int)f2bf(acc[5]) << 16);
    o.w = (unsigned int)f2bf(acc[6]) | ((unsigned int)f2bf(acc[7]) << 16);
    *(uint4*)&out[(size_t)n * D + f0] = o;
}

// ---------------- mean pool (batch sorted), bf16 input, f64 accum ----------------
__global__ __launch_bounds__(256) void k_pool(const unsigned short* __restrict__ h, const int* __restrict__ batch,
                                              double* __restrict__ sums, int* __restrict__ cnts) {
    const int NB = 256;
    const int n0 = blockIdx.x * NB;
    const int d = threadIdx.x & 63;
    const int sub = threadIdx.x >> 6;
    double acc = 0.0;
    int cnt = 0;
    int cur = -1;
    for (int i = sub; i < NB; i += 4) {
        int n = n0 + i;
        if (n >= NN) break;
        int g = batch[n];
        if (g != cur) {
            if (cur >= 0) {
                atomicAdd(&sums[cur * 64 + d], acc);
                if (d == 0) atomicAdd(&cnts[cur], cnt);
            }
            cur = g;
            acc = 0.0;
            cnt = 0;
        }
        acc += (double)bf2f(h[(size_t)n * 64 + d]);
        cnt++;
    }
    if (cur >= 0) {
        atomicAdd(&sums[cur * 64 + d], acc);
        if (d == 0) atomicAdd(&cnts[cur], cnt);
    }
}

__global__ __launch_bounds__(256) void k_final(const double* __restrict__ sums, const int* __restrict__ cnts,
                                               float* __restrict__ out) {
    int i = blockIdx.x * 256 + threadIdx.x;
    if (i >= NG * 64) return;
    int g = i >> 6;
    double c = (double)max(cnts[g], 1);
    out[i] = (float)(sums[i] / c);
}

extern "C" void kernel_launch(void* const* d_in, const int* in_sizes, int n_in,
                              void* d_out, int out_size, void* d_ws, size_t ws_size,
                              hipStream_t stream) {
    (void)in_sizes; (void)n_in; (void)out_size; (void)ws_size;
    const float* x     = (const float*)d_in[0];
    const int*   ei    = (const int*)d_in[1];
    const int*   batch = (const int*)d_in[2];
    const float* W1    = (const float*)d_in[3];
    const float* b1    = (const float*)d_in[4];
    const float* W2    = (const float*)d_in[5];
    const float* b2    = (const float*)d_in[6];
    const float* W3    = (const float*)d_in[7];
    const float* b3    = (const float*)d_in[8];
    float* out = (float*)d_out;

    // workspace layout
    char* w = (char*)d_ws;
    char*  zbase = w;
    double* psums  = (double*)w;        w += (size_t)NG * 64 * 8;
    int*    pcnts  = (int*)w;           w += 256;
    size_t zbytes = (size_t)(w - zbase);
    int*    degcnt = (int*)w;           w += (size_t)NN * 4;
    float*  dinv   = (float*)w;         w += (size_t)NN * 4;
    int*    row_ptr = (int*)w;          w += (size_t)(NN + 4) * 4;
    int*    blk_sums = (int*)w;         w += 64 * 4;
    unsigned short* rank   = (unsigned short*)w;  w += (size_t)NE * 2;
    unsigned short* percnt = (unsigned short*)w;  w += (size_t)NCHUNK * NN * 2;
    int*    csr_src = (int*)w;          w += (size_t)NE * 4;
    unsigned short* bufT = (unsigned short*)w;  w += (size_t)NN * 128 * 2;  // bf16 gather target
    unsigned short* bufA = (unsigned short*)w;  w += (size_t)NN * 128 * 2;  // bf16 agg output / GEMM input

    hipMemsetAsync(zbase, 0, zbytes, stream);

    // atomic-free CSR build
    k_hist<<<dim3(NCHUNK, 2), 1024, 0, stream>>>(ei, rank, percnt);
    k_colscan<<<(NN + 255) / 256, 256, 0, stream>>>(percnt, degcnt, dinv);
    const int nb_scan = (NN + 1023) / 1024;   // 49
    k_scan1<<<nb_scan, 1024, 0, stream>>>(degcnt, row_ptr, blk_sums);
    k_scan2<<<1, 64, 0, stream>>>(blk_sums, nb_scan);
    k_scan3<<<nb_scan, 1024, 0, stream>>>(row_ptr, blk_sums);
    k_fill3<<<(NE + 255) / 256, 256, 0, stream>>>(ei, row_ptr, rank, percnt, csr_src);

    const int gemm_grid = (NN + 63) / 64;      // 782
    const int agg_grid128 = (NN + 15) / 16;    // 3125
    const int agg_grid64  = (NN + 31) / 32;    // 1563
    // layer 1 (A = x, f32)
    k_gemm_mfma<128, true><<<gemm_grid, 256, 0, stream>>>(x, W1, bufT, NN);
    k_agg<128, true><<<agg_grid128, 256, 0, stream>>>(bufT, b1, dinv, row_ptr, csr_src, bufA);
    // layer 2 (A = bufA, bf16)
    k_gemm_mfma<128, false><<<gemm_grid, 256, 0, stream>>>(bufA, W2, bufT, NN);
    k_agg<128, true><<<agg_grid128, 256, 0, stream>>>(bufT, b2, dinv, row_ptr, csr_src, bufA);
    // layer 3 (no relu, D_OUT=64)
    k_gemm_mfma<64, false><<<gemm_grid, 256, 0, stream>>>(bufA, W3, bufT, NN);
    k_agg<64, false><<<agg_grid64, 256, 0, stream>>>(bufT, b3, dinv, row_ptr, csr_src, bufA);
    // pool
    k_pool<<<(NN + 255) / 256, 256, 0, stream>>>(bufA, batch, psums, pcnts);
    k_final<<<(NG * 64 + 255) / 256, 256, 0, stream>>>(psums, pcnts, out);
}